// Round 5
// baseline (147.811 us; speedup 1.0000x reference)
//
#include <hip/hip_runtime.h>
#include <math.h>

// Problem constants (from reference setup_inputs)
#define BB 16
#define LL 64
#define FF 60
#define DD 256
#define UU 600
#define VV 10000
#define JMAX 10
#define MINL 4
#define EE 7           // MAX_LEN - MIN_LEN + 1
#define NEG (-1e9f)
#define TH 0.05f
#define VHALF (VV / 2)

// Workspace layout (in floats). Total ~= 4.6 MB.
#define UNT_OFF   0                         // unT[256][640]  (u padded 600->640)
#define UNT_SZ    (256 * 640)
#define WNT_OFF   (UNT_OFF + UNT_SZ)        // wnT[256][1024] (bl = b*64+l)
#define WNT_SZ    (256 * 1024)
#define SIM_OFF   (WNT_OFF + WNT_SZ)        // sim[16][64][600]
#define SIM_SZ    (BB * LL * UU)
#define PK_OFF    (SIM_OFF + SIM_SZ)        // packed seg: 32B per v (8 u32)
#define PK_SZ     (VV * 8)
#define VAL_OFF   (PK_OFF + PK_SZ)          // val[2][16][64][7]  (per v-half)
#define VAL_SZ    (2 * BB * LL * EE)
#define VOC_OFF   (VAL_OFF + VAL_SZ)        // int voc[2][16][64][7]

// ---------------------------------------------------------------------------
// Pack per-v record: 10 x u16 precomputed LDS indices (u*11+j, max 6598),
// u16 vlen, pad to 32B -> two aligned dwordx4 loads in k_score.
__global__ __launch_bounds__(256) void k_pack(const int* __restrict__ seg,
                                              const int* __restrict__ vlen,
                                              unsigned int* __restrict__ pk) {
    int v = blockIdx.x * 256 + threadIdx.x;
    if (v >= VV) return;
    const int* s = seg + v * JMAX;
    unsigned int t[10];
#pragma unroll
    for (int j = 0; j < JMAX; ++j) t[j] = (unsigned int)(s[j] * 11 + j);
    unsigned int* dst = pk + v * 8;
    dst[0] = t[0] | (t[1] << 16);
    dst[1] = t[2] | (t[3] << 16);
    dst[2] = t[4] | (t[5] << 16);
    dst[3] = t[6] | (t[7] << 16);
    dst[4] = t[8] | (t[9] << 16);
    dst[5] = (unsigned int)vlen[v];
    dst[6] = 0;
    dst[7] = 0;
}

// ---------------------------------------------------------------------------
// Embed + L2-normalize rows of unit_feats (600) and x (1024), storing both
// TRANSPOSED: unT[d][u] (stride 640), wnT[d][bl] (stride 1024). One wave per
// row; lane covers 4 of the 256 output dims.
__global__ __launch_bounds__(64) void k_embed(const float* __restrict__ x,
                                              const float* __restrict__ uf,
                                              const float* __restrict__ W,
                                              float* __restrict__ unT,
                                              float* __restrict__ wnT) {
    int id = blockIdx.x;
    int lane = threadIdx.x;
    const float* row;
    float* outB;
    int stride, col;
    if (id < UU) { row = uf + id * FF; outB = unT; stride = 640;  col = id; }
    else { int bl = id - UU; row = x + bl * FF; outB = wnT; stride = 1024; col = bl; }

    float r0 = 0.f, r1 = 0.f, r2 = 0.f, r3 = 0.f;
#pragma unroll 4
    for (int f = 0; f < FF; ++f) {
        float xv = row[f];  // wave-uniform broadcast load
        r0 += xv * W[f * DD + lane];
        r1 += xv * W[f * DD + lane + 64];
        r2 += xv * W[f * DD + lane + 128];
        r3 += xv * W[f * DD + lane + 192];
    }
    float ss = r0 * r0 + r1 * r1 + r2 * r2 + r3 * r3;
#pragma unroll
    for (int m = 32; m > 0; m >>= 1) ss += __shfl_xor(ss, m, 64);
    float inv = 1.0f / (sqrtf(ss) + 1e-8f);   // matches ref x/(norm+1e-8)
    outB[(lane      ) * stride + col] = r0 * inv;
    outB[(lane +  64) * stride + col] = r1 * inv;
    outB[(lane + 128) * stride + col] = r2 * inv;
    outB[(lane + 192) * stride + col] = r3 * inv;
}

// ---------------------------------------------------------------------------
// sim[b][l][u] = wn[bl] . un[u].  1024 blocks = (b, l-pair, u-half), 320
// threads (5 waves, wave w = u-chunk w of its half). Thread tile: 2l x 1u.
// 4 blocks/CU -> 20 waves/CU for L2-latency hiding; unroll 8.
__global__ __launch_bounds__(320, 5) void k_sim(const float* __restrict__ unT,
                                                const float* __restrict__ wnT,
                                                float* __restrict__ sim) {
    int blk = blockIdx.x;
    int b  = blk >> 6;
    int r  = blk & 63;
    int l0 = (r >> 1) * 2;
    int uh = r & 1;
    int bl0 = b * 64 + l0;
    int tid = threadIdx.x;
    int w = tid >> 6;
    int lane = tid & 63;
    int u = uh * 320 + w * 64 + lane;   // < 640 (unT padded; stores guarded)

    float a0 = 0.f, a1 = 0.f;
#pragma unroll 8
    for (int d = 0; d < DD; ++d) {
        float w0 = wnT[d * 1024 + bl0 + 0];
        float w1 = wnT[d * 1024 + bl0 + 1];
        float v  = unT[d * 640 + u];
        a0 += w0 * v;
        a1 += w1 * v;
    }
    if (u < UU) {
        sim[(bl0 + 0) * UU + u] = a0;
        sim[(bl0 + 1) * UU + u] = a1;
    }
}

// ---------------------------------------------------------------------------
// Phase 3: 1024 blocks = (v-half, b, l-pair), 512 threads. Stage sim rows
// l0..l0+10 in LDS transposed [u][11] (stride 11, coprime with 32 banks),
// strided so all 600 u-rows are staged. Per v: two dwordx4 packed-index
// loads, straight-line fully-unrolled 10-step ds_read2_b32 chain, branchless
// predicated best-updates on RAW sums (divide winner once at the end).
// Each v-half writes its own val/voc slice; k_final merges (half0 = lower v
// wins ties).
__global__ __launch_bounds__(512, 8) void k_score(const float* __restrict__ sim,
                                                  const unsigned int* __restrict__ pk,
                                                  const int* __restrict__ lengths,
                                                  float* __restrict__ val,
                                                  int* __restrict__ voc) {
    __shared__ float lds[UU * 11];   // 26.4 KB -> 4 blocks/CU fits 160 KB
    __shared__ float redS[14][8];    // e*2+dl in [0,14) x 8 waves
    __shared__ int   redV[14][8];

    int blk = blockIdx.x;
    int half = blk >> 9;
    int rest = blk & 511;
    int b  = rest >> 5;
    int l0 = (rest & 31) * 2;
    int tid = threadIdx.x;

    // Stage sim tile -> LDS transposed; rows >= L are the zero-pad region.
    for (int u = tid; u < UU; u += 512) {
#pragma unroll
        for (int r = 0; r < 11; ++r) {
            int m = l0 + r;
            lds[u * 11 + r] = (m < LL) ? sim[(b * 64 + m) * UU + u] : 0.0f;
        }
    }
    __syncthreads();

    float bS[EE][2];
    int   bV[EE][2];
#pragma unroll
    for (int e = 0; e < EE; ++e) {
        bS[e][0] = -1e30f; bS[e][1] = -1e30f;
        bV[e][0] = 0;      bV[e][1] = 0;
    }

    int vend = VHALF * (half + 1);
    for (int v = VHALF * half + tid; v < vend; v += 512) {
        const uint4* pp = (const uint4*)(pk + v * 8);
        uint4 qa = pp[0];
        uint4 qb = pp[1];
        int idx[10];
        idx[0] = qa.x & 0xffff; idx[1] = qa.x >> 16;
        idx[2] = qa.y & 0xffff; idx[3] = qa.y >> 16;
        idx[4] = qa.z & 0xffff; idx[5] = qa.z >> 16;
        idx[6] = qa.w & 0xffff; idx[7] = qa.w >> 16;
        idx[8] = qb.x & 0xffff; idx[9] = qb.x >> 16;
        int k = (int)(qb.y & 0xffff);

        float a0 = 0.f, a1 = 0.f;
#pragma unroll
        for (int j = 0; j < JMAX; ++j) {
            float x0 = lds[idx[j]];
            float x1 = lds[idx[j] + 1];
            a0 += x0;
            a1 += x1;
            if (j >= MINL - 1) {
                int e = j - (MINL - 1);          // static after full unroll
                bool m = (k == j + 1);
                bool p0 = m & (a0 > bS[e][0]);
                bool p1 = m & (a1 > bS[e][1]);
                bS[e][0] = p0 ? a0 : bS[e][0];
                bV[e][0] = p0 ? v  : bV[e][0];
                bS[e][1] = p1 ? a1 : bS[e][1];
                bV[e][1] = p1 ? v  : bV[e][1];
            }
        }
    }

    int w = tid >> 6, lane = tid & 63;
#pragma unroll
    for (int e = 0; e < EE; ++e) {
#pragma unroll
        for (int dl = 0; dl < 2; ++dl) {
            float s = bS[e][dl];
            int vv = bV[e][dl];
#pragma unroll
            for (int off = 32; off > 0; off >>= 1) {
                float os = __shfl_down(s, off, 64);
                int   ov = __shfl_down(vv, off, 64);
                if (os > s || (os == s && ov < vv)) { s = os; vv = ov; }
            }
            if (lane == 0) { redS[e * 2 + dl][w] = s; redV[e * 2 + dl][w] = vv; }
        }
    }
    __syncthreads();

    if (tid < 14) {   // only indices 0..13 of redS/redV are valid
        int e  = tid >> 1;
        int dl = tid & 1;
        float s = redS[tid][0];
        int  vv = redV[tid][0];
#pragma unroll
        for (int w2 = 1; w2 < 8; ++w2) {
            float os = redS[tid][w2];
            int   ov = redV[tid][w2];
            if (os > s || (os == s && ov < vv)) { s = os; vv = ov; }
        }
        int lg = l0 + dl;
        int k = e + MINL;
        bool viable = (lg + k - 1) < lengths[b];
        float sn = s / (float)k;   // normalize winner only (bit-same as ref a/k)
        int o = (half * BB * LL + b * 64 + lg) * EE + e;
        val[o] = viable ? sn : NEG;
        voc[o] = viable ? vv : 0;  // ref argmax of all-NEG = 0
    }
}

// ---------------------------------------------------------------------------
// Per-b: merge the two v-halves slot-wise (strict > keeps half0 = lower v on
// ties), then flat argmax over the 448 (l,e) slots (min flat index on ties),
// any_matched = merged max > THRESH. Outputs written as float32 values.
__global__ __launch_bounds__(512) void k_final(const float* __restrict__ val,
                                               const int* __restrict__ voc,
                                               float* __restrict__ out) {
    __shared__ float sS[8];
    __shared__ int   sI[8];
    __shared__ int   sV[8];
    __shared__ int   sA[8];
    int b = blockIdx.x;
    int t = threadIdx.x;
    float s = -3e38f;
    int idx = 1 << 30;
    int vc = 0;
    int any = 0;
    if (t < LL * EE) {
        int o0 = b * LL * EE + t;
        int o1 = BB * LL * EE + o0;
        float s0 = val[o0], s1 = val[o1];
        bool sel = s1 > s0;                 // tie -> half0 (lower v) = ref order
        s  = sel ? s1 : s0;
        vc = sel ? voc[o1] : voc[o0];
        idx = t;
        any = (s > TH) ? 1 : 0;
    }
#pragma unroll
    for (int off = 32; off > 0; off >>= 1) {
        float os = __shfl_down(s, off, 64);
        int   oi = __shfl_down(idx, off, 64);
        int   ov = __shfl_down(vc, off, 64);
        int   oa = __shfl_down(any, off, 64);
        if (os > s || (os == s && oi < idx)) { s = os; idx = oi; vc = ov; }
        any |= oa;
    }
    int w = t >> 6, lane = t & 63;
    if (lane == 0) { sS[w] = s; sI[w] = idx; sV[w] = vc; sA[w] = any; }
    __syncthreads();
    if (t == 0) {
        for (int w2 = 1; w2 < 8; ++w2) {
            float os = sS[w2];
            int   oi = sI[w2];
            if (os > s || (os == s && oi < idx)) { s = os; idx = oi; vc = sV[w2]; }
            any |= sA[w2];
        }
        int start = idx / EE;
        int e = idx - start * EE;
        int end = e + start + MINL - 1;
        out[b]      = s;
        out[16 + b] = (float)start;
        out[32 + b] = (float)end;
        out[48 + b] = any ? 1.0f : 0.0f;
        out[64 + b] = (float)vc;
    }
}

// ---------------------------------------------------------------------------
extern "C" void kernel_launch(void* const* d_in, const int* in_sizes, int n_in,
                              void* d_out, int out_size, void* d_ws, size_t ws_size,
                              hipStream_t stream) {
    const float* x       = (const float*)d_in[0];   // [16][64][60]
    const float* uf      = (const float*)d_in[1];   // [600][60]
    const float* W       = (const float*)d_in[2];   // [60][256]
    const int*   lengths = (const int*)d_in[3];     // [16]
    const int*   seg     = (const int*)d_in[4];     // [10000][10]
    const int*   vlen    = (const int*)d_in[5];     // [10000]
    float* out = (float*)d_out;
    float* ws  = (float*)d_ws;

    float*        unT = ws + UNT_OFF;
    float*        wnT = ws + WNT_OFF;
    float*        sim = ws + SIM_OFF;
    unsigned int* pk  = (unsigned int*)(ws + PK_OFF);
    float*        val = ws + VAL_OFF;
    int*          voc = (int*)(ws + VOC_OFF);

    k_pack<<<(VV + 255) / 256, 256, 0, stream>>>(seg, vlen, pk);
    k_embed<<<UU + BB * LL, 64, 0, stream>>>(x, uf, W, unT, wnT);
    k_sim<<<1024, 320, 0, stream>>>(unT, wnT, sim);
    k_score<<<1024, 512, 0, stream>>>(sim, pk, lengths, val, voc);
    k_final<<<BB, 512, 0, stream>>>(val, voc, out);
}